// Round 1
// baseline (230.927 us; speedup 1.0000x reference)
//
#include <hip/hip_runtime.h>

// LIF recurrence, T=4, TAU=1.0, THRESH=1.0.
// mem = mem + x[t]; spike = (mem - 1 > 0); mem = spike ? 0 : mem.
// Element-wise over N spatial positions; float4-vectorized, coalesced.

#define LIF_T 4

__global__ __launch_bounds__(256) void
lif_spike_kernel(const float* __restrict__ x, float* __restrict__ out, int n_vec, int n) {
    int v = blockIdx.x * blockDim.x + threadIdx.x;
    if (v >= n_vec) return;
    size_t i = (size_t)v * 4;

    float4 mem = make_float4(0.f, 0.f, 0.f, 0.f);

#pragma unroll
    for (int t = 0; t < LIF_T; ++t) {
        const float4 xt = *reinterpret_cast<const float4*>(x + (size_t)t * n + i);
        mem.x += xt.x;
        mem.y += xt.y;
        mem.z += xt.z;
        mem.w += xt.w;

        float4 sp;
        sp.x = (mem.x > 1.0f) ? 1.0f : 0.0f;
        sp.y = (mem.y > 1.0f) ? 1.0f : 0.0f;
        sp.z = (mem.z > 1.0f) ? 1.0f : 0.0f;
        sp.w = (mem.w > 1.0f) ? 1.0f : 0.0f;

        // mem = (1 - spike) * mem  ->  reset to 0 where spiked
        mem.x = (sp.x > 0.f) ? 0.f : mem.x;
        mem.y = (sp.y > 0.f) ? 0.f : mem.y;
        mem.z = (sp.z > 0.f) ? 0.f : mem.z;
        mem.w = (sp.w > 0.f) ? 0.f : mem.w;

        *reinterpret_cast<float4*>(out + (size_t)t * n + i) = sp;
    }
}

extern "C" void kernel_launch(void* const* d_in, const int* in_sizes, int n_in,
                              void* d_out, int out_size, void* d_ws, size_t ws_size,
                              hipStream_t stream) {
    const float* x = (const float*)d_in[0];
    float* out = (float*)d_out;

    // in_sizes[0] = T * N; out_size == T * N. N is divisible by 4.
    int n = out_size / LIF_T;      // elements per timestep (8,388,608)
    int n_vec = n / 4;             // float4 groups per timestep

    int block = 256;
    int grid = (n_vec + block - 1) / block;
    lif_spike_kernel<<<grid, block, 0, stream>>>(x, out, n_vec, n);
}